// Round 3
// baseline (7704.360 us; speedup 1.0000x reference)
//
#include <hip/hip_runtime.h>

// Bidirectional masked LSTM encoder, MI355X gfx950.
// V=50000 E=300 H=256 T=512 B=64.
// Round 3: recurrence restructured. U-slices register-resident (loop
// invariant); hidden state split 8 ways across blocks per (bg); h exchanged
// as MFMA A-fragments via L2-backed global buffer + device-scope flags.
// Both directions interleaved per block to hide exchange latency.

#define T_ 512
#define B_ 64
#define E_ 300
#define FOURH 1024

typedef float floatx4 __attribute__((ext_vector_type(4)));
typedef __bf16 bf16x8 __attribute__((ext_vector_type(8)));

// ws layout (bytes):
//   xpf  (bf16 frag-packed xproj): 2*2048*64*64*4*2B = 134217728  @ 0
//   xpack(bf16): 2048*10*64*8*2 =  20971520   @ 134217728
//   wp   (bf16): 2*64*10*64*8*2 =   1310720   @ 155189248
//   up   (bf16): 2*64*8*64*8*2  =   1048576   @ 156499968
//   hx   (bf16 A-frags): 2dir*2par*4bg*8ks*1024B = 131072 @ 157548544
//   flags(int): 2*4*8*4 = 256 (padded 4096)   @ 157679616
#define WS_XPACK_OFF 134217728ull
#define WS_WP_OFF    155189248ull
#define WS_UP_OFF    156499968ull
#define WS_HX_OFF    157548544ull
#define WS_FLAG_OFF  157679616ull
#define WS_NEEDED    157683712ull

#define OUT_H_OFF    16777216ull
#define OUT_C_OFF    16809984ull
#define OUT_M_OFF    16842752ull

__device__ __forceinline__ unsigned short f2bf(float f) {
    unsigned int u = __builtin_bit_cast(unsigned int, f);
    u += 0x7fffu + ((u >> 16) & 1u);
    return (unsigned short)(u >> 16);
}
__device__ __forceinline__ float bf2f(unsigned short b) {
    unsigned int u = ((unsigned int)b) << 16;
    return __builtin_bit_cast(float, u);
}

__device__ __forceinline__ float sigf(float x) { return 1.f / (1.f + __expf(-x)); }

__device__ __forceinline__ float tanh_fast(float x) {
    float t = __expf(-2.f * fabsf(x));      // in (0,1], no overflow
    float r = (1.f - t) / (1.f + t);
    return x >= 0.f ? r : -r;
}

// ---------------- pack embedded x into A-fragment order --------------------
// xpack[mtile][ks][lane][8] bf16 ; row = mtile*16 + (l&15), k = ks*32 + (l>>4)*8 + e
// row r = t*64 + b  (time-major rows of xt[t][b])
__global__ void pack_x_kernel(const int* __restrict__ seq, const float* __restrict__ emb,
                              unsigned short* __restrict__ xpack) {
    const int mtile = blockIdx.x;   // 0..2047
    const int l = threadIdx.x;      // 0..63
    const int row = mtile * 16 + (l & 15);
    const int t = row >> 6, b = row & 63;
    const int token = seq[b * T_ + t];
    const float* src = emb + (size_t)token * E_;
    const int kb = (l >> 4) * 8;
#pragma unroll
    for (int ks = 0; ks < 10; ++ks) {
        const int k0 = ks * 32 + kb;
        unsigned int w[4];
#pragma unroll
        for (int h = 0; h < 4; ++h) {
            int ka = k0 + 2 * h, kbb = ka + 1;
            float fa = (ka < E_) ? src[ka] : 0.f;
            float fb = (kbb < E_) ? src[kbb] : 0.f;
            w[h] = (unsigned int)f2bf(fa) | ((unsigned int)f2bf(fb) << 16);
        }
        uint4* dst = reinterpret_cast<uint4*>(xpack + ((size_t)(mtile * 10 + ks) * 64 + l) * 8);
        *dst = make_uint4(w[0], w[1], w[2], w[3]);
    }
}

// ------------- pack a [Ksrc x 1024] f32 matrix into B-fragment order -------
// dst[ntile][ks][lane][8] ; n = ntile*16 + (l&15), k = ks*32 + (l>>4)*8 + e
__global__ void pack_mat_kernel(const float* __restrict__ src, unsigned short* __restrict__ dst,
                                int Ksrc, int nks) {
    const int ks = blockIdx.x;      // 0..nks-1
    const int ntile = blockIdx.y;   // 0..63
    const int l = threadIdx.x;
    const int n = ntile * 16 + (l & 15);
    const int k0 = ks * 32 + (l >> 4) * 8;
    unsigned int w[4];
#pragma unroll
    for (int h = 0; h < 4; ++h) {
        int ka = k0 + 2 * h, kb2 = ka + 1;
        float fa = (ka < Ksrc) ? src[(size_t)ka * FOURH + n] : 0.f;
        float fb = (kb2 < Ksrc) ? src[(size_t)kb2 * FOURH + n] : 0.f;
        w[h] = (unsigned int)f2bf(fa) | ((unsigned int)f2bf(fb) << 16);
    }
    uint4* d = reinterpret_cast<uint4*>(dst + ((size_t)(ntile * nks + ks) * 64 + l) * 8);
    *d = make_uint4(w[0], w[1], w[2], w[3]);
}

// ---------------- xproj = xpack @ Wpack + bias  (LDS-free MFMA GEMM) -------
// Output stored FRAGMENT-PACKED: xpf[dir][mt][nt][lane][4 bf16] (C-layout),
// so the recurrence reads one uint2 per lane per tile.
__global__ __launch_bounds__(256) void gemm_xproj_kernel(
    const unsigned short* __restrict__ xpack, const unsigned short* __restrict__ wp,
    const float* __restrict__ b_fw, const float* __restrict__ b_bw,
    unsigned short* __restrict__ xpf) {
    const int bid = blockIdx.x;
    const int dir = bid >> 11;          // 2048 blocks per dir
    const int rem = bid & 2047;
    const int mb = rem >> 3;            // 0..255
    const int nb = rem & 7;             // 0..7
    const int w = threadIdx.x >> 6;
    const int l = threadIdx.x & 63;
    const int wm = w >> 1, wn = w & 1;
    const unsigned short* wpd = wp + (size_t)dir * (64 * 10 * 64 * 8);
    const float* bias = dir ? b_bw : b_fw;

    floatx4 acc[4][4];
#pragma unroll
    for (int i = 0; i < 4; ++i)
#pragma unroll
        for (int j = 0; j < 4; ++j) acc[i][j] = floatx4{0.f, 0.f, 0.f, 0.f};

#pragma unroll
    for (int ks = 0; ks < 10; ++ks) {
        bf16x8 a[4], bb[4];
#pragma unroll
        for (int mi = 0; mi < 4; ++mi) {
            int mt = mb * 8 + wm * 4 + mi;
            a[mi] = *reinterpret_cast<const bf16x8*>(xpack + ((size_t)(mt * 10 + ks) * 64 + l) * 8);
        }
#pragma unroll
        for (int ni = 0; ni < 4; ++ni) {
            int nt = nb * 8 + wn * 4 + ni;
            bb[ni] = *reinterpret_cast<const bf16x8*>(wpd + ((size_t)(nt * 10 + ks) * 64 + l) * 8);
        }
#pragma unroll
        for (int mi = 0; mi < 4; ++mi)
#pragma unroll
            for (int ni = 0; ni < 4; ++ni)
                acc[mi][ni] = __builtin_amdgcn_mfma_f32_16x16x32_bf16(a[mi], bb[ni], acc[mi][ni], 0, 0, 0);
    }

    unsigned short* xpd = xpf + (size_t)dir * 33554432ull;
#pragma unroll
    for (int mi = 0; mi < 4; ++mi) {
        int mt = mb * 8 + wm * 4 + mi;
#pragma unroll
        for (int ni = 0; ni < 4; ++ni) {
            int nt = nb * 8 + wn * 4 + ni;
            float bv = bias[nt * 16 + (l & 15)];
            unsigned int w0 = (unsigned int)f2bf(acc[mi][ni][0] + bv) |
                              ((unsigned int)f2bf(acc[mi][ni][1] + bv) << 16);
            unsigned int w1 = (unsigned int)f2bf(acc[mi][ni][2] + bv) |
                              ((unsigned int)f2bf(acc[mi][ni][3] + bv) << 16);
            *reinterpret_cast<uint2*>(xpd + (((size_t)mt * 64 + nt) * 64 + l) * 4) = make_uint2(w0, w1);
        }
    }
}

// ---------------- recurrent LSTM: 32 blocks = 4 bg x 8 cg, both dirs -------
// Each block: 16 batch rows (bg), 32 hidden cols (cg), both directions.
// U B-frags register-resident. h exchanged as A-frags via hx[] + flags.
__global__ __launch_bounds__(512, 1) void lstm_rec_kernel(
    const int* __restrict__ seq, const unsigned short* __restrict__ xpf,
    const unsigned short* __restrict__ up, unsigned short* __restrict__ hx,
    int* __restrict__ flags, float* __restrict__ out) {
    const int bid = blockIdx.x;     // 0..31 ; bg = bid&3 -> group on XCDs {bg, bg+4}
    const int bg = bid & 3;
    const int cg = bid >> 2;        // 0..7
    const int tid = threadIdx.x;
    const int w = tid >> 6;         // wave 0..7 : gate = w>>1, half = w&1
    const int l = tid & 63;
    const int g = w >> 1, sub = w & 1;
    const int nt = g * 16 + cg * 2 + sub;   // global z ntile (of 64)
    const int row = tid >> 5;       // gates-phase cell row 0..15
    const int colc = tid & 31;      // gates-phase local h col 0..31
    const int bgl = bg * 16 + row;  // global batch row of this cell

    __shared__ __align__(16) float zbuf[8][16][17];
    __shared__ __align__(16) unsigned short hnew[512];

    // U B-fragments (loop-invariant, registers): per dir 8 ks-frags
    bf16x8 Bf[2][8];
#pragma unroll
    for (int d = 0; d < 2; ++d) {
        const unsigned short* ub = up + (size_t)d * 262144 + (size_t)nt * 4096 + (size_t)l * 8;
#pragma unroll
        for (int ks = 0; ks < 8; ++ks)
            Bf[d][ks] = *reinterpret_cast<const bf16x8*>(ub + (size_t)ks * 512);
    }

    uint4 afrag[2][8];
#pragma unroll
    for (int d = 0; d < 2; ++d)
#pragma unroll
        for (int ks = 0; ks < 8; ++ks) afrag[d][ks] = make_uint4(0, 0, 0, 0);

    float h_s[2] = {0.f, 0.f}, c_s[2] = {0.f, 0.f};

    // xq / tok prefetch (wave view for xq, cell view for tok)
    uint2 xq_c[2], xq_n[2];
    int tok_c[2], tok_n[2];
    {
        size_t mt0 = (size_t)0 * 4 + bg, mt1 = (size_t)511 * 4 + bg;
        xq_c[0] = *reinterpret_cast<const uint2*>(xpf + ((mt0 * 64 + nt) * 64 + l) * 4);
        xq_c[1] = *reinterpret_cast<const uint2*>(xpf + 33554432ull + ((mt1 * 64 + nt) * 64 + l) * 4);
        tok_c[0] = seq[bgl * T_ + 0];
        tok_c[1] = seq[bgl * T_ + 511];
    }

    for (int s = 0; s < 512; ++s) {
#pragma unroll
        for (int d = 0; d < 2; ++d) {
            const int t = d ? (511 - s) : s;

            floatx4 acc;
            acc[0] = bf2f((unsigned short)(xq_c[d].x & 0xffff));
            acc[1] = bf2f((unsigned short)(xq_c[d].x >> 16));
            acc[2] = bf2f((unsigned short)(xq_c[d].y & 0xffff));
            acc[3] = bf2f((unsigned short)(xq_c[d].y >> 16));
#pragma unroll
            for (int ks = 0; ks < 8; ++ks)
                acc = __builtin_amdgcn_mfma_f32_16x16x32_bf16(
                    __builtin_bit_cast(bf16x8, afrag[d][ks]), Bf[d][ks], acc, 0, 0, 0);

            // prefetch next step's xq/tok for this dir (hides HBM latency)
            if (s + 1 < 512) {
                int tn = d ? (511 - (s + 1)) : (s + 1);
                size_t mtn = (size_t)tn * 4 + bg;
                xq_n[d] = *reinterpret_cast<const uint2*>(
                    xpf + (size_t)d * 33554432ull + ((mtn * 64 + nt) * 64 + l) * 4);
                tok_n[d] = seq[bgl * T_ + tn];
            }

            // z -> LDS (C-layout: col=l&15, row=(l>>4)*4+e)
#pragma unroll
            for (int e = 0; e < 4; ++e)
                zbuf[w][(l >> 4) * 4 + e][l & 15] = acc[e];
            __syncthreads();

            // gates (cell view: one cell per thread)
            {
                int hs2 = colc >> 4, hc = colc & 15;
                float zi = zbuf[0 + hs2][row][hc];
                float zf = zbuf[2 + hs2][row][hc];
                float zg = zbuf[4 + hs2][row][hc];
                float zo = zbuf[6 + hs2][row][hc];
                float ig = sigf(zi), fg = sigf(zf), gg = tanh_fast(zg), og = sigf(zo);
                float cn = fg * c_s[d] + ig * gg;
                float hn = og * tanh_fast(cn);
                if (tok_c[d] != 0) { c_s[d] = cn; h_s[d] = hn; }
                out[((size_t)(bgl * T_ + t)) * 512 + (size_t)d * 256 + cg * 32 + colc] = h_s[d];
                hnew[((colc >> 3) * 16 + row) * 8 + (colc & 7)] = f2bf(h_s[d]);
            }
            __syncthreads();

            // publish our h-slice as an A-fragment (k-slice cg)
            if (w == 0 && s + 1 < 512) {
                uint4 v = *reinterpret_cast<const uint4*>(&hnew[l * 8]);
                unsigned short* dst = hx +
                    (((size_t)(d * 2 + ((s + 1) & 1)) * 32 + bg * 8 + cg) * 512 + (size_t)l * 8);
                *reinterpret_cast<uint4*>(dst) = v;
                __threadfence();
                if (l == 0)
                    __hip_atomic_store(&flags[d * 32 + bg * 8 + cg], s + 1,
                                       __ATOMIC_RELEASE, __HIP_MEMORY_SCOPE_AGENT);
            }
        }

        // gather all 8 k-slices of h for next step (both dirs)
        if (s + 1 < 512) {
            const int target = s + 1, pr = (s + 1) & 1;
#pragma unroll
            for (int d = 0; d < 2; ++d) {
                int fidx = d * 32 + bg * 8 + (l & 7);
                int fl;
                do {
                    fl = __hip_atomic_load(&flags[fidx], __ATOMIC_RELAXED, __HIP_MEMORY_SCOPE_AGENT);
                } while (!__all(fl >= target));
            }
            __threadfence();
#pragma unroll
            for (int d = 0; d < 2; ++d)
#pragma unroll
                for (int ks = 0; ks < 8; ++ks) {
                    const unsigned int* src = reinterpret_cast<const unsigned int*>(
                        hx + (((size_t)(d * 2 + pr) * 32 + bg * 8 + ks) * 512 + (size_t)l * 8));
                    afrag[d][ks].x = __hip_atomic_load(src + 0, __ATOMIC_RELAXED, __HIP_MEMORY_SCOPE_AGENT);
                    afrag[d][ks].y = __hip_atomic_load(src + 1, __ATOMIC_RELAXED, __HIP_MEMORY_SCOPE_AGENT);
                    afrag[d][ks].z = __hip_atomic_load(src + 2, __ATOMIC_RELAXED, __HIP_MEMORY_SCOPE_AGENT);
                    afrag[d][ks].w = __hip_atomic_load(src + 3, __ATOMIC_RELAXED, __HIP_MEMORY_SCOPE_AGENT);
                }
            xq_c[0] = xq_n[0]; xq_c[1] = xq_n[1];
            tok_c[0] = tok_n[0]; tok_c[1] = tok_n[1];
        }
    }

    // final carried states
#pragma unroll
    for (int d = 0; d < 2; ++d) {
        out[OUT_H_OFF + (size_t)bgl * 512 + (size_t)d * 256 + cg * 32 + colc] = h_s[d];
        out[OUT_C_OFF + (size_t)bgl * 512 + (size_t)d * 256 + cg * 32 + colc] = c_s[d];
    }
}

// ---------------- mask output ----------------------------------------------
__global__ void mask_kernel(const int* __restrict__ seq, float* __restrict__ out) {
    int i = blockIdx.x * 256 + threadIdx.x;
    if (i < B_ * T_) out[OUT_M_OFF + i] = (seq[i] != 0) ? 1.0f : 0.0f;
}

extern "C" void kernel_launch(void* const* d_in, const int* in_sizes, int n_in,
                              void* d_out, int out_size, void* d_ws, size_t ws_size,
                              hipStream_t stream) {
    const int* seq = (const int*)d_in[0];
    // d_in[1]=state_h0, d_in[2]=state_c0: unused by the reference (zero init)
    const float* emb  = (const float*)d_in[3];
    const float* W_fw = (const float*)d_in[4];
    const float* U_fw = (const float*)d_in[5];
    const float* b_fw = (const float*)d_in[6];
    const float* W_bw = (const float*)d_in[7];
    const float* U_bw = (const float*)d_in[8];
    const float* b_bw = (const float*)d_in[9];
    float* out = (float*)d_out;

    // Always produce the mask (writes only to d_out).
    hipLaunchKernelGGL(mask_kernel, dim3(128), dim3(256), 0, stream, seq, out);

    if (ws_size < WS_NEEDED) return;    // diagnostic bail-out

    char* ws = (char*)d_ws;
    unsigned short* xpf   = (unsigned short*)ws;
    unsigned short* xpack = (unsigned short*)(ws + WS_XPACK_OFF);
    unsigned short* wp    = (unsigned short*)(ws + WS_WP_OFF);
    unsigned short* up    = (unsigned short*)(ws + WS_UP_OFF);
    unsigned short* hx    = (unsigned short*)(ws + WS_HX_OFF);
    int* flags            = (int*)(ws + WS_FLAG_OFF);

    // zero h-exchange buffers + flags (replay-safe)
    hipMemsetAsync((void*)(ws + WS_HX_OFF), 0, 135168, stream);

    hipLaunchKernelGGL(pack_x_kernel, dim3(2048), dim3(64), 0, stream, seq, emb, xpack);
    hipLaunchKernelGGL(pack_mat_kernel, dim3(10, 64), dim3(64), 0, stream, W_fw, wp,          300, 10);
    hipLaunchKernelGGL(pack_mat_kernel, dim3(10, 64), dim3(64), 0, stream, W_bw, wp + 327680, 300, 10);
    hipLaunchKernelGGL(pack_mat_kernel, dim3(8, 64),  dim3(64), 0, stream, U_fw, up,          256, 8);
    hipLaunchKernelGGL(pack_mat_kernel, dim3(8, 64),  dim3(64), 0, stream, U_bw, up + 262144, 256, 8);
    hipLaunchKernelGGL(gemm_xproj_kernel, dim3(4096), dim3(256), 0, stream, xpack, wp, b_fw, b_bw, xpf);
    hipLaunchKernelGGL(lstm_rec_kernel, dim3(32), dim3(512), 0, stream, seq, xpf, up, hx, flags, out);
}

// Round 4
// 5043.468 us; speedup vs baseline: 1.5276x; 1.5276x over previous
//
#include <hip/hip_runtime.h>

// Bidirectional masked LSTM encoder, MI355X gfx950.
// V=50000 E=300 H=256 T=512 B=64.
// Round 4: 8 independent blocks (4 bg x 2 dir), 1024 thr = 16 waves = 1 CU.
// U register-resident (128 VGPR/wave, loop-invariant). Wave w owns h-cols
// [16w,16w+16) for ALL 4 gates -> gates computed in-wave, no z roundtrip.
// h double-buffered in XOR-swizzled LDS; one barrier per step.

#define T_ 512
#define B_ 64
#define E_ 300
#define FOURH 1024

typedef float floatx4 __attribute__((ext_vector_type(4)));
typedef __bf16 bf16x8 __attribute__((ext_vector_type(8)));

// ws layout (bytes):
//   xpf  (bf16 frag-packed xproj): 2*2048*64*64*4*2B = 134217728  @ 0
//   xpack(bf16): 2048*10*64*8*2 =  20971520   @ 134217728
//   wp   (bf16): 2*64*10*64*8*2 =   1310720   @ 155189248
//   up   (bf16): 2*64*8*64*8*2  =   1048576   @ 156499968
#define WS_XPACK_OFF 134217728ull
#define WS_WP_OFF    155189248ull
#define WS_UP_OFF    156499968ull
#define WS_NEEDED    157548544ull

#define OUT_H_OFF    16777216ull
#define OUT_C_OFF    16809984ull
#define OUT_M_OFF    16842752ull

__device__ __forceinline__ unsigned short f2bf(float f) {
    unsigned int u = __builtin_bit_cast(unsigned int, f);
    u += 0x7fffu + ((u >> 16) & 1u);
    return (unsigned short)(u >> 16);
}
__device__ __forceinline__ float bf2f(unsigned short b) {
    unsigned int u = ((unsigned int)b) << 16;
    return __builtin_bit_cast(float, u);
}

__device__ __forceinline__ float sigf(float x) { return 1.f / (1.f + __expf(-x)); }

__device__ __forceinline__ float tanh_fast(float x) {
    float t = __expf(-2.f * fabsf(x));      // in (0,1], no overflow
    float r = (1.f - t) / (1.f + t);
    return x >= 0.f ? r : -r;
}

// ---------------- pack embedded x into A-fragment order --------------------
// xpack[mtile][ks][lane][8] bf16 ; row = mtile*16 + (l&15), k = ks*32 + (l>>4)*8 + e
// row r = t*64 + b  (time-major rows of xt[t][b])
__global__ void pack_x_kernel(const int* __restrict__ seq, const float* __restrict__ emb,
                              unsigned short* __restrict__ xpack) {
    const int mtile = blockIdx.x;   // 0..2047
    const int l = threadIdx.x;      // 0..63
    const int row = mtile * 16 + (l & 15);
    const int t = row >> 6, b = row & 63;
    const int token = seq[b * T_ + t];
    const float* src = emb + (size_t)token * E_;
    const int kb = (l >> 4) * 8;
#pragma unroll
    for (int ks = 0; ks < 10; ++ks) {
        const int k0 = ks * 32 + kb;
        unsigned int w[4];
#pragma unroll
        for (int h = 0; h < 4; ++h) {
            int ka = k0 + 2 * h, kbb = ka + 1;
            float fa = (ka < E_) ? src[ka] : 0.f;
            float fb = (kbb < E_) ? src[kbb] : 0.f;
            w[h] = (unsigned int)f2bf(fa) | ((unsigned int)f2bf(fb) << 16);
        }
        uint4* dst = reinterpret_cast<uint4*>(xpack + ((size_t)(mtile * 10 + ks) * 64 + l) * 8);
        *dst = make_uint4(w[0], w[1], w[2], w[3]);
    }
}

// ------------- pack a [Ksrc x 1024] f32 matrix into B-fragment order -------
// dst[ntile][ks][lane][8] ; n = ntile*16 + (l&15), k = ks*32 + (l>>4)*8 + e
__global__ void pack_mat_kernel(const float* __restrict__ src, unsigned short* __restrict__ dst,
                                int Ksrc, int nks) {
    const int ks = blockIdx.x;      // 0..nks-1
    const int ntile = blockIdx.y;   // 0..63
    const int l = threadIdx.x;
    const int n = ntile * 16 + (l & 15);
    const int k0 = ks * 32 + (l >> 4) * 8;
    unsigned int w[4];
#pragma unroll
    for (int h = 0; h < 4; ++h) {
        int ka = k0 + 2 * h, kb2 = ka + 1;
        float fa = (ka < Ksrc) ? src[(size_t)ka * FOURH + n] : 0.f;
        float fb = (kb2 < Ksrc) ? src[(size_t)kb2 * FOURH + n] : 0.f;
        w[h] = (unsigned int)f2bf(fa) | ((unsigned int)f2bf(fb) << 16);
    }
    uint4* d = reinterpret_cast<uint4*>(dst + ((size_t)(ntile * nks + ks) * 64 + l) * 8);
    *d = make_uint4(w[0], w[1], w[2], w[3]);
}

// ---------------- xproj = xpack @ Wpack + bias  (LDS-free MFMA GEMM) -------
// Output stored FRAGMENT-PACKED: xpf[dir][mt][nt][lane][4 bf16] (C-layout).
__global__ __launch_bounds__(256) void gemm_xproj_kernel(
    const unsigned short* __restrict__ xpack, const unsigned short* __restrict__ wp,
    const float* __restrict__ b_fw, const float* __restrict__ b_bw,
    unsigned short* __restrict__ xpf) {
    const int bid = blockIdx.x;
    const int dir = bid >> 11;          // 2048 blocks per dir
    const int rem = bid & 2047;
    const int mb = rem >> 3;            // 0..255
    const int nb = rem & 7;             // 0..7
    const int w = threadIdx.x >> 6;
    const int l = threadIdx.x & 63;
    const int wm = w >> 1, wn = w & 1;
    const unsigned short* wpd = wp + (size_t)dir * (64 * 10 * 64 * 8);
    const float* bias = dir ? b_bw : b_fw;

    floatx4 acc[4][4];
#pragma unroll
    for (int i = 0; i < 4; ++i)
#pragma unroll
        for (int j = 0; j < 4; ++j) acc[i][j] = floatx4{0.f, 0.f, 0.f, 0.f};

#pragma unroll
    for (int ks = 0; ks < 10; ++ks) {
        bf16x8 a[4], bb[4];
#pragma unroll
        for (int mi = 0; mi < 4; ++mi) {
            int mt = mb * 8 + wm * 4 + mi;
            a[mi] = *reinterpret_cast<const bf16x8*>(xpack + ((size_t)(mt * 10 + ks) * 64 + l) * 8);
        }
#pragma unroll
        for (int ni = 0; ni < 4; ++ni) {
            int nt = nb * 8 + wn * 4 + ni;
            bb[ni] = *reinterpret_cast<const bf16x8*>(wpd + ((size_t)(nt * 10 + ks) * 64 + l) * 8);
        }
#pragma unroll
        for (int mi = 0; mi < 4; ++mi)
#pragma unroll
            for (int ni = 0; ni < 4; ++ni)
                acc[mi][ni] = __builtin_amdgcn_mfma_f32_16x16x32_bf16(a[mi], bb[ni], acc[mi][ni], 0, 0, 0);
    }

    unsigned short* xpd = xpf + (size_t)dir * 33554432ull;
#pragma unroll
    for (int mi = 0; mi < 4; ++mi) {
        int mt = mb * 8 + wm * 4 + mi;
#pragma unroll
        for (int ni = 0; ni < 4; ++ni) {
            int nt = nb * 8 + wn * 4 + ni;
            float bv = bias[nt * 16 + (l & 15)];
            unsigned int w0 = (unsigned int)f2bf(acc[mi][ni][0] + bv) |
                              ((unsigned int)f2bf(acc[mi][ni][1] + bv) << 16);
            unsigned int w1 = (unsigned int)f2bf(acc[mi][ni][2] + bv) |
                              ((unsigned int)f2bf(acc[mi][ni][3] + bv) << 16);
            *reinterpret_cast<uint2*>(xpd + (((size_t)mt * 64 + nt) * 64 + l) * 4) = make_uint2(w0, w1);
        }
    }
}

// ---------------- recurrent LSTM: 8 blocks x 1024 threads ------------------
// Block = (bg, dir). Wave w (0..15) owns h-coltile w for all 4 gates.
// U B-frags in registers (loop-invariant). h dbuf in swizzled LDS.
__global__ __launch_bounds__(1024, 1) void lstm_rec_kernel(
    const int* __restrict__ seq, const unsigned short* __restrict__ xpf,
    const unsigned short* __restrict__ up, float* __restrict__ out) {
    const int blk = blockIdx.x;     // 0..7
    const int dir = blk >> 2;
    const int bg = blk & 3;
    const int tid = threadIdx.x;
    const int w = tid >> 6;         // 0..15 = h-coltile
    const int l = tid & 63;
    const unsigned short* xpd = xpf + (size_t)dir * 33554432ull;
    const unsigned short* upd = up + (size_t)dir * 262144;

    __shared__ __align__(16) unsigned short hbuf[2][16 * 256];
    for (int i = tid; i < 16 * 256; i += 1024) hbuf[0][i] = 0;
    __syncthreads();

    // U B-fragments: nt = g*16 + w, 8 k-steps each -> 128 VGPR, loop-invariant
    bf16x8 Bf[4][8];
#pragma unroll
    for (int g = 0; g < 4; ++g) {
        const unsigned short* ub = upd + (size_t)(g * 16 + w) * 4096 + (size_t)l * 8;
#pragma unroll
        for (int ks = 0; ks < 8; ++ks)
            Bf[g][ks] = *reinterpret_cast<const bf16x8*>(ub + (size_t)ks * 512);
    }

    const int rrb = (l >> 4) * 4;       // rows rrb..rrb+3 (batch-local)
    const int hc = w * 16 + (l & 15);   // h column 0..255
    const int arow = l & 15;
    const int akb = (l >> 4) * 8;
    const int axor = (arow & 7) << 3;   // ushort-unit xor

    float h_s[4], c_s[4];
#pragma unroll
    for (int e = 0; e < 4; ++e) { h_s[e] = 0.f; c_s[e] = 0.f; }

    // prefetch xq + tokens for step 0
    uint2 xq_c[4], xq_n[4];
    int tok_c[4], tok_n[4];
    {
        int t0 = dir ? 511 : 0;
        size_t mt0 = (size_t)t0 * 4 + bg;
#pragma unroll
        for (int g = 0; g < 4; ++g)
            xq_c[g] = *reinterpret_cast<const uint2*>(xpd + ((mt0 * 64 + (g * 16 + w)) * 64 + l) * 4);
#pragma unroll
        for (int e = 0; e < 4; ++e) tok_c[e] = seq[(bg * 16 + rrb + e) * T_ + t0];
    }

    int p = 0;
    for (int s = 0; s < 512; ++s) {
        const int t = dir ? (511 - s) : s;

        // A-fragments (h of previous step) from swizzled LDS
        bf16x8 a[8];
#pragma unroll
        for (int ks = 0; ks < 8; ++ks)
            a[ks] = *reinterpret_cast<const bf16x8*>(&hbuf[p][arow * 256 + ((ks * 32 + akb) ^ axor)]);

        floatx4 acc[4];
#pragma unroll
        for (int g = 0; g < 4; ++g) {
            floatx4 v;
            v[0] = bf2f((unsigned short)(xq_c[g].x & 0xffff));
            v[1] = bf2f((unsigned short)(xq_c[g].x >> 16));
            v[2] = bf2f((unsigned short)(xq_c[g].y & 0xffff));
            v[3] = bf2f((unsigned short)(xq_c[g].y >> 16));
            acc[g] = v;
        }
#pragma unroll
        for (int ks = 0; ks < 8; ++ks)
#pragma unroll
            for (int g = 0; g < 4; ++g)
                acc[g] = __builtin_amdgcn_mfma_f32_16x16x32_bf16(a[ks], Bf[g][ks], acc[g], 0, 0, 0);

        // prefetch next step's xq/tok (hides HBM latency under gates)
        if (s + 1 < 512) {
            int tn = dir ? (511 - (s + 1)) : (s + 1);
            size_t mtn = (size_t)tn * 4 + bg;
#pragma unroll
            for (int g = 0; g < 4; ++g)
                xq_n[g] = *reinterpret_cast<const uint2*>(xpd + ((mtn * 64 + (g * 16 + w)) * 64 + l) * 4);
#pragma unroll
            for (int e = 0; e < 4; ++e) tok_n[e] = seq[(bg * 16 + rrb + e) * T_ + tn];
        }

        // gates + masked state update + writes (4 cells per lane)
#pragma unroll
        for (int e = 0; e < 4; ++e) {
            float ig = sigf(acc[0][e]);
            float fg = sigf(acc[1][e]);
            float gg = tanh_fast(acc[2][e]);
            float og = sigf(acc[3][e]);
            float cn = fg * c_s[e] + ig * gg;
            float hn = og * tanh_fast(cn);
            if (tok_c[e] != 0) { c_s[e] = cn; h_s[e] = hn; }
            int r = rrb + e;
            out[((size_t)((bg * 16 + r) * T_ + t)) * 512 + (size_t)dir * 256 + hc] = h_s[e];
            hbuf[p ^ 1][r * 256 + (hc ^ ((r & 7) << 3))] = f2bf(h_s[e]);
        }
        __syncthreads();
        p ^= 1;
#pragma unroll
        for (int g = 0; g < 4; ++g) xq_c[g] = xq_n[g];
#pragma unroll
        for (int e = 0; e < 4; ++e) tok_c[e] = tok_n[e];
    }

    // final carried states
#pragma unroll
    for (int e = 0; e < 4; ++e) {
        int b = bg * 16 + rrb + e;
        out[OUT_H_OFF + (size_t)b * 512 + (size_t)dir * 256 + hc] = h_s[e];
        out[OUT_C_OFF + (size_t)b * 512 + (size_t)dir * 256 + hc] = c_s[e];
    }
}

// ---------------- mask output ----------------------------------------------
__global__ void mask_kernel(const int* __restrict__ seq, float* __restrict__ out) {
    int i = blockIdx.x * 256 + threadIdx.x;
    if (i < B_ * T_) out[OUT_M_OFF + i] = (seq[i] != 0) ? 1.0f : 0.0f;
}

extern "C" void kernel_launch(void* const* d_in, const int* in_sizes, int n_in,
                              void* d_out, int out_size, void* d_ws, size_t ws_size,
                              hipStream_t stream) {
    const int* seq = (const int*)d_in[0];
    // d_in[1]=state_h0, d_in[2]=state_c0: unused by the reference (zero init)
    const float* emb  = (const float*)d_in[3];
    const float* W_fw = (const float*)d_in[4];
    const float* U_fw = (const float*)d_in[5];
    const float* b_fw = (const float*)d_in[6];
    const float* W_bw = (const float*)d_in[7];
    const float* U_bw = (const float*)d_in[8];
    const float* b_bw = (const float*)d_in[9];
    float* out = (float*)d_out;

    // Always produce the mask (writes only to d_out).
    hipLaunchKernelGGL(mask_kernel, dim3(128), dim3(256), 0, stream, seq, out);

    if (ws_size < WS_NEEDED) return;    // diagnostic bail-out

    char* ws = (char*)d_ws;
    unsigned short* xpf   = (unsigned short*)ws;
    unsigned short* xpack = (unsigned short*)(ws + WS_XPACK_OFF);
    unsigned short* wp    = (unsigned short*)(ws + WS_WP_OFF);
    unsigned short* up    = (unsigned short*)(ws + WS_UP_OFF);

    hipLaunchKernelGGL(pack_x_kernel, dim3(2048), dim3(64), 0, stream, seq, emb, xpack);
    hipLaunchKernelGGL(pack_mat_kernel, dim3(10, 64), dim3(64), 0, stream, W_fw, wp,          300, 10);
    hipLaunchKernelGGL(pack_mat_kernel, dim3(10, 64), dim3(64), 0, stream, W_bw, wp + 327680, 300, 10);
    hipLaunchKernelGGL(pack_mat_kernel, dim3(8, 64),  dim3(64), 0, stream, U_fw, up,          256, 8);
    hipLaunchKernelGGL(pack_mat_kernel, dim3(8, 64),  dim3(64), 0, stream, U_bw, up + 262144, 256, 8);
    hipLaunchKernelGGL(gemm_xproj_kernel, dim3(4096), dim3(256), 0, stream, xpack, wp, b_fw, b_bw, xpf);
    hipLaunchKernelGGL(lstm_rec_kernel, dim3(8), dim3(1024), 0, stream, seq, xpf, up, out);
}

// Round 5
// 1781.186 us; speedup vs baseline: 4.3254x; 2.8315x over previous
//
#include <hip/hip_runtime.h>

// Bidirectional masked LSTM encoder, MI355X gfx950.
// V=50000 E=300 H=256 T=512 B=64.
// Round 5: 16 blocks = 4bg x 2dir x 2 col-halves, 512 thr (8 waves, 2/SIMD,
// 256-VGPR cap). Each block's U-half (256 KB) fully register-resident
// (128 VGPR/wave). Per step the 4 KB h-half is exchanged with the sibling
// block via system-scope relaxed atomics (L3 coherence point) + flag sync.

#define T_ 512
#define B_ 64
#define E_ 300
#define FOURH 1024

typedef float floatx4 __attribute__((ext_vector_type(4)));
typedef __bf16 bf16x8 __attribute__((ext_vector_type(8)));

// ws layout (bytes):
//   xpf  (bf16 frag-packed xproj): 2*2048*64*64*4*2B = 134217728  @ 0
//   xpack(bf16): 2048*10*64*8*2 =  20971520   @ 134217728
//   wp   (bf16): 2*64*10*64*8*2 =   1310720   @ 155189248
//   up   (bf16): 2*64*8*64*8*2  =   1048576   @ 156499968
//   hx   : 8 pairs * 2 halves * 2 parity * 4096 B = 131072 @ 157548544
//   flags: 16 ints (padded 4096) @ 157679616
#define WS_XPACK_OFF 134217728ull
#define WS_WP_OFF    155189248ull
#define WS_UP_OFF    156499968ull
#define WS_HX_OFF    157548544ull
#define WS_FLAG_OFF  157679616ull
#define WS_NEEDED    157683712ull

#define OUT_H_OFF    16777216ull
#define OUT_C_OFF    16809984ull
#define OUT_M_OFF    16842752ull

__device__ __forceinline__ unsigned short f2bf(float f) {
    unsigned int u = __builtin_bit_cast(unsigned int, f);
    u += 0x7fffu + ((u >> 16) & 1u);
    return (unsigned short)(u >> 16);
}
__device__ __forceinline__ float bf2f(unsigned short b) {
    unsigned int u = ((unsigned int)b) << 16;
    return __builtin_bit_cast(float, u);
}

__device__ __forceinline__ float sigf(float x) { return 1.f / (1.f + __expf(-x)); }

__device__ __forceinline__ float tanh_fast(float x) {
    float t = __expf(-2.f * fabsf(x));      // in (0,1], no overflow
    float r = (1.f - t) / (1.f + t);
    return x >= 0.f ? r : -r;
}

// ---------------- pack embedded x into A-fragment order --------------------
__global__ void pack_x_kernel(const int* __restrict__ seq, const float* __restrict__ emb,
                              unsigned short* __restrict__ xpack) {
    const int mtile = blockIdx.x;   // 0..2047
    const int l = threadIdx.x;      // 0..63
    const int row = mtile * 16 + (l & 15);
    const int t = row >> 6, b = row & 63;
    const int token = seq[b * T_ + t];
    const float* src = emb + (size_t)token * E_;
    const int kb = (l >> 4) * 8;
#pragma unroll
    for (int ks = 0; ks < 10; ++ks) {
        const int k0 = ks * 32 + kb;
        unsigned int w[4];
#pragma unroll
        for (int h = 0; h < 4; ++h) {
            int ka = k0 + 2 * h, kbb = ka + 1;
            float fa = (ka < E_) ? src[ka] : 0.f;
            float fb = (kbb < E_) ? src[kbb] : 0.f;
            w[h] = (unsigned int)f2bf(fa) | ((unsigned int)f2bf(fb) << 16);
        }
        uint4* dst = reinterpret_cast<uint4*>(xpack + ((size_t)(mtile * 10 + ks) * 64 + l) * 8);
        *dst = make_uint4(w[0], w[1], w[2], w[3]);
    }
}

// ------------- pack a [Ksrc x 1024] f32 matrix into B-fragment order -------
__global__ void pack_mat_kernel(const float* __restrict__ src, unsigned short* __restrict__ dst,
                                int Ksrc, int nks) {
    const int ks = blockIdx.x;      // 0..nks-1
    const int ntile = blockIdx.y;   // 0..63
    const int l = threadIdx.x;
    const int n = ntile * 16 + (l & 15);
    const int k0 = ks * 32 + (l >> 4) * 8;
    unsigned int w[4];
#pragma unroll
    for (int h = 0; h < 4; ++h) {
        int ka = k0 + 2 * h, kb2 = ka + 1;
        float fa = (ka < Ksrc) ? src[(size_t)ka * FOURH + n] : 0.f;
        float fb = (kb2 < Ksrc) ? src[(size_t)kb2 * FOURH + n] : 0.f;
        w[h] = (unsigned int)f2bf(fa) | ((unsigned int)f2bf(fb) << 16);
    }
    uint4* d = reinterpret_cast<uint4*>(dst + ((size_t)(ntile * nks + ks) * 64 + l) * 8);
    *d = make_uint4(w[0], w[1], w[2], w[3]);
}

// ---------------- xproj = xpack @ Wpack + bias  (LDS-free MFMA GEMM) -------
__global__ __launch_bounds__(256) void gemm_xproj_kernel(
    const unsigned short* __restrict__ xpack, const unsigned short* __restrict__ wp,
    const float* __restrict__ b_fw, const float* __restrict__ b_bw,
    unsigned short* __restrict__ xpf) {
    const int bid = blockIdx.x;
    const int dir = bid >> 11;          // 2048 blocks per dir
    const int rem = bid & 2047;
    const int mb = rem >> 3;            // 0..255
    const int nb = rem & 7;             // 0..7
    const int w = threadIdx.x >> 6;
    const int l = threadIdx.x & 63;
    const int wm = w >> 1, wn = w & 1;
    const unsigned short* wpd = wp + (size_t)dir * (64 * 10 * 64 * 8);
    const float* bias = dir ? b_bw : b_fw;

    floatx4 acc[4][4];
#pragma unroll
    for (int i = 0; i < 4; ++i)
#pragma unroll
        for (int j = 0; j < 4; ++j) acc[i][j] = floatx4{0.f, 0.f, 0.f, 0.f};

#pragma unroll
    for (int ks = 0; ks < 10; ++ks) {
        bf16x8 a[4], bb[4];
#pragma unroll
        for (int mi = 0; mi < 4; ++mi) {
            int mt = mb * 8 + wm * 4 + mi;
            a[mi] = *reinterpret_cast<const bf16x8*>(xpack + ((size_t)(mt * 10 + ks) * 64 + l) * 8);
        }
#pragma unroll
        for (int ni = 0; ni < 4; ++ni) {
            int nt = nb * 8 + wn * 4 + ni;
            bb[ni] = *reinterpret_cast<const bf16x8*>(wpd + ((size_t)(nt * 10 + ks) * 64 + l) * 8);
        }
#pragma unroll
        for (int mi = 0; mi < 4; ++mi)
#pragma unroll
            for (int ni = 0; ni < 4; ++ni)
                acc[mi][ni] = __builtin_amdgcn_mfma_f32_16x16x32_bf16(a[mi], bb[ni], acc[mi][ni], 0, 0, 0);
    }

    unsigned short* xpd = xpf + (size_t)dir * 33554432ull;
#pragma unroll
    for (int mi = 0; mi < 4; ++mi) {
        int mt = mb * 8 + wm * 4 + mi;
#pragma unroll
        for (int ni = 0; ni < 4; ++ni) {
            int nt = nb * 8 + wn * 4 + ni;
            float bv = bias[nt * 16 + (l & 15)];
            unsigned int w0 = (unsigned int)f2bf(acc[mi][ni][0] + bv) |
                              ((unsigned int)f2bf(acc[mi][ni][1] + bv) << 16);
            unsigned int w1 = (unsigned int)f2bf(acc[mi][ni][2] + bv) |
                              ((unsigned int)f2bf(acc[mi][ni][3] + bv) << 16);
            *reinterpret_cast<uint2*>(xpd + (((size_t)mt * 64 + nt) * 64 + l) * 4) = make_uint2(w0, w1);
        }
    }
}

// ---------------- recurrent LSTM: 16 blocks = 8 chains x 2 col-halves ------
// Block (pairIdx = bg*2+dir, half). 512 thr = 8 waves; wave w owns h-coltile
// hct = half*8+w for all 4 gates -> U frags Bf[4][8] = 128 VGPR resident.
// Per step: 4 KB h-half exchanged with sibling via system-scope atomics.
__global__ __launch_bounds__(512, 2) void lstm_rec_kernel(
    const int* __restrict__ seq, const unsigned short* __restrict__ xpf,
    const unsigned short* __restrict__ up, unsigned long long* __restrict__ hx,
    int* __restrict__ flags, float* __restrict__ out) {
    const int bid = blockIdx.x;     // 0..15 ; sibling at bid^8 (same XCD mod-8)
    const int half = bid >> 3;
    const int pairIdx = bid & 7;
    const int bg = pairIdx >> 1;
    const int dir = pairIdx & 1;
    const int sib = 1 - half;
    const int tid = threadIdx.x;
    const int w = tid >> 6;         // 0..7
    const int l = tid & 63;
    const int hct = half * 8 + w;   // h-coltile 0..15
    const unsigned short* xpd = xpf + (size_t)dir * 33554432ull;
    const unsigned short* upd = up + (size_t)dir * 262144;

    __shared__ __align__(16) unsigned short hbuf[2][16 * 256];
    for (int i = tid; i < 16 * 256; i += 512) hbuf[0][i] = 0;

    // U B-fragments, register-resident (128 VGPR)
    bf16x8 Bf[4][8];
#pragma unroll
    for (int g = 0; g < 4; ++g) {
        const unsigned short* ub = upd + (size_t)(g * 16 + hct) * 4096 + (size_t)l * 8;
#pragma unroll
        for (int ks = 0; ks < 8; ++ks)
            Bf[g][ks] = *reinterpret_cast<const bf16x8*>(ub + (size_t)ks * 512);
    }

    const int rrb = (l >> 4) * 4;       // cell rows rrb..rrb+3 (batch-local)
    const int hc = hct * 16 + (l & 15); // h column 0..255
    const int arow = l & 15;
    const int akb = (l >> 4) * 8;
    const int axor = (arow & 7) << 3;

    // exchange geometry (per thread: one uint2 = 4 ushorts of one row)
    const int rowp = tid >> 5;              // 0..15
    const int c4 = (tid & 31) * 4;          // 0..124
    const int swzp = (rowp & 7) << 3;
    const int myslot  = (pairIdx * 2 + half) * 2;   // + parity
    const int sibslot = (pairIdx * 2 + sib) * 2;
    int* myflag  = &flags[pairIdx * 2 + half];
    int* sibflag = &flags[pairIdx * 2 + sib];

    float h_s[4], c_s[4];
#pragma unroll
    for (int e = 0; e < 4; ++e) { h_s[e] = 0.f; c_s[e] = 0.f; }

    // prefetch xq + tokens for step 0
    uint2 xq_c[4], xq_n[4];
    int tok_c[4], tok_n[4];
    {
        int t0 = dir ? 511 : 0;
        size_t mt0 = (size_t)t0 * 4 + bg;
#pragma unroll
        for (int g = 0; g < 4; ++g)
            xq_c[g] = *reinterpret_cast<const uint2*>(
                xpd + ((mt0 * 64 + (g * 16 + hct)) * 64 + l) * 4);
#pragma unroll
        for (int e = 0; e < 4; ++e) tok_c[e] = seq[(bg * 16 + rrb + e) * T_ + t0];
    }
    __syncthreads();

    int p = 0;
    for (int s = 0; s < 512; ++s) {
        const int t = dir ? (511 - s) : s;

        // A-fragments (full h of previous step) from swizzled LDS
        bf16x8 a[8];
#pragma unroll
        for (int ks = 0; ks < 8; ++ks)
            a[ks] = *reinterpret_cast<const bf16x8*>(&hbuf[p][arow * 256 + ((ks * 32 + akb) ^ axor)]);

        floatx4 acc[4];
#pragma unroll
        for (int g = 0; g < 4; ++g) {
            floatx4 v;
            v[0] = bf2f((unsigned short)(xq_c[g].x & 0xffff));
            v[1] = bf2f((unsigned short)(xq_c[g].x >> 16));
            v[2] = bf2f((unsigned short)(xq_c[g].y & 0xffff));
            v[3] = bf2f((unsigned short)(xq_c[g].y >> 16));
            acc[g] = v;
        }
#pragma unroll
        for (int ks = 0; ks < 8; ++ks)
#pragma unroll
            for (int g = 0; g < 4; ++g)
                acc[g] = __builtin_amdgcn_mfma_f32_16x16x32_bf16(a[ks], Bf[g][ks], acc[g], 0, 0, 0);

        // prefetch next step's xq/tok (overlaps with exchange wait)
        if (s + 1 < 512) {
            int tn = dir ? (511 - (s + 1)) : (s + 1);
            size_t mtn = (size_t)tn * 4 + bg;
#pragma unroll
            for (int g = 0; g < 4; ++g)
                xq_n[g] = *reinterpret_cast<const uint2*>(
                    xpd + ((mtn * 64 + (g * 16 + hct)) * 64 + l) * 4);
#pragma unroll
            for (int e = 0; e < 4; ++e) tok_n[e] = seq[(bg * 16 + rrb + e) * T_ + tn];
        }

        // gates + masked state update + out/hbuf writes (own 16 cols)
#pragma unroll
        for (int e = 0; e < 4; ++e) {
            float ig = sigf(acc[0][e]);
            float fg = sigf(acc[1][e]);
            float gg = tanh_fast(acc[2][e]);
            float og = sigf(acc[3][e]);
            float cn = fg * c_s[e] + ig * gg;
            float hn = og * tanh_fast(cn);
            if (tok_c[e] != 0) { c_s[e] = cn; h_s[e] = hn; }
            int r = rrb + e;
            out[((size_t)((bg * 16 + r) * T_ + t)) * 512 + (size_t)dir * 256 + hc] = h_s[e];
            hbuf[p ^ 1][r * 256 + (hc ^ ((r & 7) << 3))] = f2bf(h_s[e]);
        }

        if (s + 1 < 512) {
            const int parity = (s + 1) & 1;
            __syncthreads();    // own-half hbuf[p^1] complete

            // publish own 4 KB half (linear row-major) via system-scope stores
            {
                unsigned long long v = *reinterpret_cast<const unsigned long long*>(
                    &hbuf[p ^ 1][rowp * 256 + ((half * 128 + c4) ^ swzp)]);
                __hip_atomic_store(&hx[(size_t)(myslot + parity) * 512 + tid], v,
                                   __ATOMIC_RELAXED, __HIP_MEMORY_SCOPE_SYSTEM);
            }
            asm volatile("s_waitcnt vmcnt(0)" ::: "memory");
            __syncthreads();    // all publish stores complete
            if (tid == 0)
                __hip_atomic_store(myflag, s + 1, __ATOMIC_RELAXED, __HIP_MEMORY_SCOPE_SYSTEM);

            // poll sibling flag (bounded), then gather its 4 KB half
            {
                int fl, guard = 0;
                do {
                    fl = __hip_atomic_load(sibflag, __ATOMIC_RELAXED, __HIP_MEMORY_SCOPE_SYSTEM);
                } while (fl < s + 1 && ++guard < 16384);
            }
            asm volatile("" ::: "memory");
            {
                unsigned long long v = __hip_atomic_load(
                    &hx[(size_t)(sibslot + parity) * 512 + tid],
                    __ATOMIC_RELAXED, __HIP_MEMORY_SCOPE_SYSTEM);
                *reinterpret_cast<unsigned long long*>(
                    &hbuf[p ^ 1][rowp * 256 + ((sib * 128 + c4) ^ swzp)]) = v;
            }
            __syncthreads();    // sibling half landed in LDS
        }

        p ^= 1;
#pragma unroll
        for (int g = 0; g < 4; ++g) xq_c[g] = xq_n[g];
#pragma unroll
        for (int e = 0; e < 4; ++e) tok_c[e] = tok_n[e];
    }

    // final carried states
#pragma unroll
    for (int e = 0; e < 4; ++e) {
        int b = bg * 16 + rrb + e;
        out[OUT_H_OFF + (size_t)b * 512 + (size_t)dir * 256 + hc] = h_s[e];
        out[OUT_C_OFF + (size_t)b * 512 + (size_t)dir * 256 + hc] = c_s[e];
    }
}

// ---------------- mask output ----------------------------------------------
__global__ void mask_kernel(const int* __restrict__ seq, float* __restrict__ out) {
    int i = blockIdx.x * 256 + threadIdx.x;
    if (i < B_ * T_) out[OUT_M_OFF + i] = (seq[i] != 0) ? 1.0f : 0.0f;
}

extern "C" void kernel_launch(void* const* d_in, const int* in_sizes, int n_in,
                              void* d_out, int out_size, void* d_ws, size_t ws_size,
                              hipStream_t stream) {
    const int* seq = (const int*)d_in[0];
    // d_in[1]=state_h0, d_in[2]=state_c0: unused by the reference (zero init)
    const float* emb  = (const float*)d_in[3];
    const float* W_fw = (const float*)d_in[4];
    const float* U_fw = (const float*)d_in[5];
    const float* b_fw = (const float*)d_in[6];
    const float* W_bw = (const float*)d_in[7];
    const float* U_bw = (const float*)d_in[8];
    const float* b_bw = (const float*)d_in[9];
    float* out = (float*)d_out;

    // Always produce the mask (writes only to d_out).
    hipLaunchKernelGGL(mask_kernel, dim3(128), dim3(256), 0, stream, seq, out);

    if (ws_size < WS_NEEDED) return;    // diagnostic bail-out

    char* ws = (char*)d_ws;
    unsigned short* xpf   = (unsigned short*)ws;
    unsigned short* xpack = (unsigned short*)(ws + WS_XPACK_OFF);
    unsigned short* wp    = (unsigned short*)(ws + WS_WP_OFF);
    unsigned short* up    = (unsigned short*)(ws + WS_UP_OFF);
    unsigned long long* hx = (unsigned long long*)(ws + WS_HX_OFF);
    int* flags            = (int*)(ws + WS_FLAG_OFF);

    // reset sync flags every launch (graph-replay safe)
    hipMemsetAsync((void*)(ws + WS_FLAG_OFF), 0, 4096, stream);

    hipLaunchKernelGGL(pack_x_kernel, dim3(2048), dim3(64), 0, stream, seq, emb, xpack);
    hipLaunchKernelGGL(pack_mat_kernel, dim3(10, 64), dim3(64), 0, stream, W_fw, wp,          300, 10);
    hipLaunchKernelGGL(pack_mat_kernel, dim3(10, 64), dim3(64), 0, stream, W_bw, wp + 327680, 300, 10);
    hipLaunchKernelGGL(pack_mat_kernel, dim3(8, 64),  dim3(64), 0, stream, U_fw, up,          256, 8);
    hipLaunchKernelGGL(pack_mat_kernel, dim3(8, 64),  dim3(64), 0, stream, U_bw, up + 262144, 256, 8);
    hipLaunchKernelGGL(gemm_xproj_kernel, dim3(4096), dim3(256), 0, stream, xpack, wp, b_fw, b_bw, xpf);
    hipLaunchKernelGGL(lstm_rec_kernel, dim3(16), dim3(512), 0, stream, seq, xpf, up, hx, flags, out);
}